// Round 3
// baseline (292.791 us; speedup 1.0000x reference)
//
#include <hip/hip_runtime.h>
#include <hip/hip_bf16.h>

#define BATCH 64
#define SEQT  512
#define EMB   1024
#define HID   2048
#define VOC   32000

using bf16x8 = __attribute__((ext_vector_type(8))) __bf16;
using f32x4  = __attribute__((ext_vector_type(4))) float;

__device__ __forceinline__ void split2(float x, __bf16& hi, __bf16& lo) {
  hi = (__bf16)x;
  lo = (__bf16)(x - (float)hi);
}

// ---------------------------------------------------------------------------
// Layer kernel: h_out = tanh(A @ W + bias), split-bf16 (hi+lo planes,
// 3 MFMA products; f32 accumulate).
// Grid: 128 blocks (one 16-col N-tile each) x 1024 thr = 16 waves.
// Wave w owns K-chunk KTOT/16 -> 64x16 partial via MFMA; LDS reduce;
// epilogue = bias + tanh + split-store.  16-way K-split gives 2048 waves
// (vs 1024 before) and 4 waves/SIMD on the 128 busy CUs.
// ---------------------------------------------------------------------------
template <int KTOT, bool GATHER>
__global__ __launch_bounds__(1024) void layer_kernel(
    const int* __restrict__ X, const float* __restrict__ emb,
    const __hip_bfloat16* __restrict__ hin_hi,
    const __hip_bfloat16* __restrict__ hin_lo,
    const float* __restrict__ W, const float* __restrict__ bias,
    __hip_bfloat16* __restrict__ hout_hi,
    __hip_bfloat16* __restrict__ hout_lo) {
  constexpr int KCHUNK = KTOT / 16;
  constexpr int KSTEPS = KCHUNK / 32;
  __shared__ float red[16 * 16 * 72];  // [wave][n][m padded 64->72]

  const int tid = threadIdx.x;
  const int w = tid >> 6;
  const int l = tid & 63;
  const int ln = l & 15;
  const int lg = l >> 4;
  const int n0 = blockIdx.x * 16;

  f32x4 acc[4];
#pragma unroll
  for (int mt = 0; mt < 4; ++mt) acc[mt] = f32x4{0.f, 0.f, 0.f, 0.f};

  const float* grow[4];
#pragma unroll
  for (int mt = 0; mt < 4; ++mt) {
    if constexpr (GATHER) {
      const int m = ln + 16 * mt;
      const int tok = X[m * SEQT + (SEQT - 1)];
      grow[mt] = emb + (size_t)tok * EMB;
    } else {
      grow[mt] = nullptr;
    }
  }

  const int kwave = w * KCHUNK + lg * 8;
  const float* Wc = W + n0 + ln;

#pragma unroll
  for (int ks = 0; ks < KSTEPS; ++ks) {
    const int kb = kwave + ks * 32;
    float bv[8];
#pragma unroll
    for (int i = 0; i < 8; ++i) bv[i] = Wc[(size_t)(kb + i) * HID];
    bf16x8 bhi, blo;
#pragma unroll
    for (int i = 0; i < 8; ++i) {
      __bf16 h_, l_;
      split2(bv[i], h_, l_);
      bhi[i] = h_;
      blo[i] = l_;
    }

#pragma unroll
    for (int mt = 0; mt < 4; ++mt) {
      bf16x8 ahi, alo;
      if constexpr (GATHER) {
#pragma unroll
        for (int i = 0; i < 8; ++i) {
          __bf16 h_, l_;
          split2(grow[mt][kb + i], h_, l_);
          ahi[i] = h_;
          alo[i] = l_;
        }
      } else {
        const size_t off = (size_t)(ln + 16 * mt) * KTOT + kb;
        ahi = *reinterpret_cast<const bf16x8*>(hin_hi + off);
        alo = *reinterpret_cast<const bf16x8*>(hin_lo + off);
      }
      acc[mt] = __builtin_amdgcn_mfma_f32_16x16x32_bf16(ahi, bhi, acc[mt], 0, 0, 0);
      acc[mt] = __builtin_amdgcn_mfma_f32_16x16x32_bf16(alo, bhi, acc[mt], 0, 0, 0);
      acc[mt] = __builtin_amdgcn_mfma_f32_16x16x32_bf16(ahi, blo, acc[mt], 0, 0, 0);
    }
  }

  // stash partials: red[(w*16 + n)*72 + m]; acc[mt][j] -> m = mt*16 + lg*4 + j
  float* dst = &red[(w * 16 + ln) * 72 + lg * 4];
#pragma unroll
  for (int mt = 0; mt < 4; ++mt)
    *reinterpret_cast<f32x4*>(dst + mt * 16) = acc[mt];

  __syncthreads();

  // 1024 outputs, 1024 threads: one each
  {
    const int m = tid >> 4, n = tid & 15;
    float s = 0.f;
#pragma unroll
    for (int ww = 0; ww < 16; ++ww) s += red[(ww * 16 + n) * 72 + m];
    s += bias[n0 + n];
    const float hval = tanhf(s);
    __bf16 h_, l_;
    split2(hval, h_, l_);
    const size_t off = (size_t)m * HID + (n0 + n);
    hout_hi[off] = *reinterpret_cast<__hip_bfloat16*>(&h_);
    hout_lo[off] = *reinterpret_cast<__hip_bfloat16*>(&l_);
  }
}

// ---------------------------------------------------------------------------
// Output kernel: out[64][VOC] = h @ W_hy + b_y, split-bf16 (3 products).
// Grid: 2000 blocks x 256 thr (4 waves). Block owns one 16-col N-tile;
// wave w owns K-chunk 512 (4-way K-split), LDS reduce, bias, store.
// 8000 waves -> ~98% occupancy; W_hy streamed f32 nontemporal (262 MB
// dominates total runtime); h (0.5 MB hi+lo) stays L2-resident.
// ---------------------------------------------------------------------------
__global__ __launch_bounds__(256) void out_kernel(
    const __hip_bfloat16* __restrict__ h_hi,
    const __hip_bfloat16* __restrict__ h_lo, const float* __restrict__ Why,
    const float* __restrict__ by, float* __restrict__ out) {
  __shared__ float red[4 * 16 * 72];  // [wave][n][m padded 64->72]

  const int tid = threadIdx.x;
  const int w = tid >> 6;
  const int l = tid & 63;
  const int ln = l & 15;
  const int lg = l >> 4;
  const int n0 = blockIdx.x * 16;

  f32x4 acc[4];
#pragma unroll
  for (int mt = 0; mt < 4; ++mt) acc[mt] = f32x4{0.f, 0.f, 0.f, 0.f};

  const float* Wc = Why + n0 + ln;
  const int kwave = w * 512 + lg * 8;

#pragma unroll 2
  for (int ks = 0; ks < 16; ++ks) {
    const int kb = kwave + ks * 32;
    float bv[8];
#pragma unroll
    for (int i = 0; i < 8; ++i)
      bv[i] = __builtin_nontemporal_load(Wc + (size_t)(kb + i) * VOC);
    bf16x8 bhi, blo;
#pragma unroll
    for (int i = 0; i < 8; ++i) {
      __bf16 h_, l_;
      split2(bv[i], h_, l_);
      bhi[i] = h_;
      blo[i] = l_;
    }

#pragma unroll
    for (int mt = 0; mt < 4; ++mt) {
      const size_t off = (size_t)(ln + 16 * mt) * HID + kb;
      const bf16x8 ahi = *reinterpret_cast<const bf16x8*>(h_hi + off);
      const bf16x8 alo = *reinterpret_cast<const bf16x8*>(h_lo + off);
      acc[mt] = __builtin_amdgcn_mfma_f32_16x16x32_bf16(ahi, bhi, acc[mt], 0, 0, 0);
      acc[mt] = __builtin_amdgcn_mfma_f32_16x16x32_bf16(alo, bhi, acc[mt], 0, 0, 0);
      acc[mt] = __builtin_amdgcn_mfma_f32_16x16x32_bf16(ahi, blo, acc[mt], 0, 0, 0);
    }
  }

  // stash partials
  float* dst = &red[(w * 16 + ln) * 72 + lg * 4];
#pragma unroll
  for (int mt = 0; mt < 4; ++mt)
    *reinterpret_cast<f32x4*>(dst + mt * 16) = acc[mt];

  __syncthreads();

  // 1024 outputs, 256 threads: 4 each; consecutive tid -> consecutive n
#pragma unroll
  for (int r = 0; r < 4; ++r) {
    const int o = tid + r * 256;
    const int m = o >> 4, n = o & 15;
    float s = 0.f;
#pragma unroll
    for (int ww = 0; ww < 4; ++ww) s += red[(ww * 16 + n) * 72 + m];
    s += by[n0 + n];
    __builtin_nontemporal_store(s, out + (size_t)m * VOC + (n0 + n));
  }
}

extern "C" void kernel_launch(void* const* d_in, const int* in_sizes, int n_in,
                              void* d_out, int out_size, void* d_ws,
                              size_t ws_size, hipStream_t stream) {
  const int* X = (const int*)d_in[0];
  const float* emb = (const float*)d_in[1];
  const float* W_xh = (const float*)d_in[2];
  const float* W_hh = (const float*)d_in[3];
  const float* W_hy = (const float*)d_in[4];
  const float* b_h = (const float*)d_in[5];
  const float* b_y = (const float*)d_in[6];
  float* out = (float*)d_out;

  __hip_bfloat16* hA_hi = (__hip_bfloat16*)d_ws;
  __hip_bfloat16* hA_lo = hA_hi + BATCH * HID;
  __hip_bfloat16* hB_hi = hA_lo + BATCH * HID;
  __hip_bfloat16* hB_lo = hB_hi + BATCH * HID;

  dim3 blk(1024), grd(128);
  layer_kernel<EMB, true><<<grd, blk, 0, stream>>>(
      X, emb, nullptr, nullptr, W_xh, b_h, hA_hi, hA_lo);
  layer_kernel<HID, false><<<grd, blk, 0, stream>>>(
      nullptr, nullptr, hA_hi, hA_lo, W_hh, b_h, hB_hi, hB_lo);
  layer_kernel<HID, false><<<grd, blk, 0, stream>>>(
      nullptr, nullptr, hB_hi, hB_lo, W_hh, b_h, hA_hi, hA_lo);
  layer_kernel<HID, false><<<grd, blk, 0, stream>>>(
      nullptr, nullptr, hA_hi, hA_lo, W_hh, b_h, hB_hi, hB_lo);
  layer_kernel<HID, false><<<grd, blk, 0, stream>>>(
      nullptr, nullptr, hB_hi, hB_lo, W_hh, b_h, hA_hi, hA_lo);
  out_kernel<<<dim3(2000), dim3(256), 0, stream>>>(hA_hi, hA_lo, W_hy, b_y, out);
}

// Round 4
// 234.315 us; speedup vs baseline: 1.2496x; 1.2496x over previous
//
#include <hip/hip_runtime.h>
#include <hip/hip_bf16.h>

#define BATCH 64
#define SEQT  512
#define EMB   1024
#define HID   2048
#define VOC   32000

using bf16x8 = __attribute__((ext_vector_type(8))) __bf16;
using f32x4  = __attribute__((ext_vector_type(4))) float;
using f32x16 = __attribute__((ext_vector_type(16))) float;

__device__ __forceinline__ void split2(float x, __bf16& hi, __bf16& lo) {
  hi = (__bf16)x;
  lo = (__bf16)(x - (float)hi);
}

// ---------------------------------------------------------------------------
// Layer kernel: h_out = tanh(A @ W + bias), split-bf16 (3 MFMA products,
// f32 accumulate), 16x16x32 MFMA (verified layout).
// Grid: 128 blocks (one 16-col N-tile) x 1024 thr = 16 waves; wave w owns
// K-chunk KTOT/16. ALL W loads of the chunk are hoisted ahead of compute
// (<=32 regs) so the L3/HBM latency is exposed once, not per-step.
// ---------------------------------------------------------------------------
template <int KTOT, bool GATHER>
__global__ __launch_bounds__(1024) void layer_kernel(
    const int* __restrict__ X, const float* __restrict__ emb,
    const __hip_bfloat16* __restrict__ hin_hi,
    const __hip_bfloat16* __restrict__ hin_lo,
    const float* __restrict__ W, const float* __restrict__ bias,
    __hip_bfloat16* __restrict__ hout_hi,
    __hip_bfloat16* __restrict__ hout_lo) {
  constexpr int KCHUNK = KTOT / 16;   // 128 (HID) or 64 (EMB)
  constexpr int KSTEPS = KCHUNK / 32; // 4 or 2
  __shared__ float red[16 * 16 * 72]; // [wave][n][m pad 72]

  const int tid = threadIdx.x;
  const int w = tid >> 6;
  const int l = tid & 63;
  const int ln = l & 15;
  const int lg = l >> 4;
  const int n0 = blockIdx.x * 16;

  f32x4 acc[4];
#pragma unroll
  for (int mt = 0; mt < 4; ++mt) acc[mt] = f32x4{0.f, 0.f, 0.f, 0.f};

  const float* grow[4];
#pragma unroll
  for (int mt = 0; mt < 4; ++mt) {
    if constexpr (GATHER) {
      const int m = ln + 16 * mt;
      const int tok = X[m * SEQT + (SEQT - 1)];
      grow[mt] = emb + (size_t)tok * EMB;
    } else {
      grow[mt] = nullptr;
    }
  }

  const int kwave = w * KCHUNK + lg * 8;
  const float* Wc = W + n0 + ln;

  // ---- hoist ALL W loads for this wave's K-chunk (issued back-to-back) ----
  float wv[KSTEPS * 8];
#pragma unroll
  for (int j = 0; j < KSTEPS * 8; ++j)
    wv[j] = Wc[(size_t)(kwave + (j >> 3) * 32 + (j & 7)) * HID];

  // ---- gather layer: hoist A (embedding rows) as float4 too ----
  f32x4 gv[GATHER ? KSTEPS * 8 : 1];
  if constexpr (GATHER) {
#pragma unroll
    for (int ks = 0; ks < KSTEPS; ++ks)
#pragma unroll
      for (int mt = 0; mt < 4; ++mt) {
        const float* p = grow[mt] + kwave + ks * 32;
        gv[(ks * 4 + mt) * 2 + 0] = *reinterpret_cast<const f32x4*>(p);
        gv[(ks * 4 + mt) * 2 + 1] = *reinterpret_cast<const f32x4*>(p + 4);
      }
  }

#pragma unroll
  for (int ks = 0; ks < KSTEPS; ++ks) {
    bf16x8 bhi, blo;
#pragma unroll
    for (int i = 0; i < 8; ++i) {
      __bf16 h_, l_;
      split2(wv[ks * 8 + i], h_, l_);
      bhi[i] = h_;
      blo[i] = l_;
    }
    const int kb = kwave + ks * 32;

#pragma unroll
    for (int mt = 0; mt < 4; ++mt) {
      bf16x8 ahi, alo;
      if constexpr (GATHER) {
        const f32x4 v0 = gv[(ks * 4 + mt) * 2 + 0];
        const f32x4 v1 = gv[(ks * 4 + mt) * 2 + 1];
#pragma unroll
        for (int i = 0; i < 4; ++i) {
          __bf16 h_, l_;
          split2(v0[i], h_, l_);
          ahi[i] = h_; alo[i] = l_;
          split2(v1[i], h_, l_);
          ahi[4 + i] = h_; alo[4 + i] = l_;
        }
      } else {
        const size_t off = (size_t)(ln + 16 * mt) * KTOT + kb;
        ahi = *reinterpret_cast<const bf16x8*>(hin_hi + off);
        alo = *reinterpret_cast<const bf16x8*>(hin_lo + off);
      }
      acc[mt] = __builtin_amdgcn_mfma_f32_16x16x32_bf16(ahi, bhi, acc[mt], 0, 0, 0);
      acc[mt] = __builtin_amdgcn_mfma_f32_16x16x32_bf16(alo, bhi, acc[mt], 0, 0, 0);
      acc[mt] = __builtin_amdgcn_mfma_f32_16x16x32_bf16(ahi, blo, acc[mt], 0, 0, 0);
    }
  }

  float* dst = &red[(w * 16 + ln) * 72 + lg * 4];
#pragma unroll
  for (int mt = 0; mt < 4; ++mt)
    *reinterpret_cast<f32x4*>(dst + mt * 16) = acc[mt];

  __syncthreads();

  {
    const int m = tid >> 4, n = tid & 15;
    float s = 0.f;
#pragma unroll
    for (int ww = 0; ww < 16; ++ww) s += red[(ww * 16 + n) * 72 + m];
    s += bias[n0 + n];
    const float hval = tanhf(s);
    __bf16 h_, l_;
    split2(hval, h_, l_);
    const size_t off = (size_t)m * HID + (n0 + n);
    hout_hi[off] = *reinterpret_cast<__hip_bfloat16*>(&h_);
    hout_lo[off] = *reinterpret_cast<__hip_bfloat16*>(&l_);
  }
}

// ---------------------------------------------------------------------------
// Output kernel: out[64][VOC] = h @ W_hy + b_y, split-bf16, 32x32x16 MFMA.
// Grid: 1000 blocks (32-col N-tile) x 256 thr (4 waves, K-split 4).
// Per k-step each load instr covers 128 B contiguous per W row (32 lanes);
// next step's 8 W loads are prefetched into fresh regs before the MFMAs so
// 8 HBM loads stay in flight per wave at all times. h stays L2-resident.
// ---------------------------------------------------------------------------
__global__ __launch_bounds__(256) void out_kernel(
    const __hip_bfloat16* __restrict__ h_hi,
    const __hip_bfloat16* __restrict__ h_lo, const float* __restrict__ Why,
    const float* __restrict__ by, float* __restrict__ out) {
  __shared__ float red[4 * 32 * 72];  // [wave][n(32)][m pad 72]

  const int tid = threadIdx.x;
  const int w = tid >> 6;
  const int l = tid & 63;
  const int ln = l & 31;
  const int lg = l >> 5;
  const int n0 = blockIdx.x * 32;

  f32x16 acc0, acc1;
#pragma unroll
  for (int i = 0; i < 16; ++i) {
    acc0[i] = 0.f;
    acc1[i] = 0.f;
  }

  const float* Wc = Why + n0 + ln;
  const int wk0 = w * 512;
  const int krow0 = wk0 + lg * 8;  // this lane's first W row

  float wcur[8];
#pragma unroll
  for (int i = 0; i < 8; ++i)
    wcur[i] = __builtin_nontemporal_load(Wc + (size_t)(krow0 + i) * VOC);

#pragma unroll 2
  for (int ks = 0; ks < 32; ++ks) {
    const size_t aoff = (size_t)(wk0 + ks * 16 + lg * 8);
    // A-frags from L2-resident h (issued first)
    const bf16x8 ah0 = *reinterpret_cast<const bf16x8*>(h_hi + (size_t)ln * HID + aoff);
    const bf16x8 al0 = *reinterpret_cast<const bf16x8*>(h_lo + (size_t)ln * HID + aoff);
    const bf16x8 ah1 = *reinterpret_cast<const bf16x8*>(h_hi + (size_t)(ln + 32) * HID + aoff);
    const bf16x8 al1 = *reinterpret_cast<const bf16x8*>(h_lo + (size_t)(ln + 32) * HID + aoff);

    // prefetch next step's W (stays in flight across the MFMAs below)
    float wnxt[8];
#pragma unroll
    for (int i = 0; i < 8; ++i) {
      const int r = (krow0 + (ks + 1) * 16 + i) & (HID - 1);  // wrap at tail
      wnxt[i] = __builtin_nontemporal_load(Wc + (size_t)r * VOC);
    }

    bf16x8 bhi, blo;
#pragma unroll
    for (int i = 0; i < 8; ++i) {
      __bf16 h_, l_;
      split2(wcur[i], h_, l_);
      bhi[i] = h_;
      blo[i] = l_;
    }

    acc0 = __builtin_amdgcn_mfma_f32_32x32x16_bf16(ah0, bhi, acc0, 0, 0, 0);
    acc0 = __builtin_amdgcn_mfma_f32_32x32x16_bf16(al0, bhi, acc0, 0, 0, 0);
    acc0 = __builtin_amdgcn_mfma_f32_32x32x16_bf16(ah0, blo, acc0, 0, 0, 0);
    acc1 = __builtin_amdgcn_mfma_f32_32x32x16_bf16(ah1, bhi, acc1, 0, 0, 0);
    acc1 = __builtin_amdgcn_mfma_f32_32x32x16_bf16(al1, bhi, acc1, 0, 0, 0);
    acc1 = __builtin_amdgcn_mfma_f32_32x32x16_bf16(ah1, blo, acc1, 0, 0, 0);

#pragma unroll
    for (int i = 0; i < 8; ++i) wcur[i] = wnxt[i];
  }

  // C/D layout: col=l&31, row=(r&3)+8*(r>>2)+4*lg -> m = mt*32 + row
  float* base = &red[(w * 32 + ln) * 72];
#pragma unroll
  for (int q = 0; q < 4; ++q) {
    f32x4 v0{acc0[4 * q], acc0[4 * q + 1], acc0[4 * q + 2], acc0[4 * q + 3]};
    f32x4 v1{acc1[4 * q], acc1[4 * q + 1], acc1[4 * q + 2], acc1[4 * q + 3]};
    *reinterpret_cast<f32x4*>(base + 8 * q + 4 * lg) = v0;
    *reinterpret_cast<f32x4*>(base + 32 + 8 * q + 4 * lg) = v1;
  }

  __syncthreads();

  // 2048 outputs (64 m x 32 n), 256 threads: 8 each, n fastest (coalesced)
#pragma unroll
  for (int r = 0; r < 8; ++r) {
    const int o = tid + r * 256;
    const int n = o & 31, m = o >> 5;
    float s = by[n0 + n];
#pragma unroll
    for (int ww = 0; ww < 4; ++ww) s += red[(ww * 32 + n) * 72 + m];
    __builtin_nontemporal_store(s, out + (size_t)m * VOC + (n0 + n));
  }
}

extern "C" void kernel_launch(void* const* d_in, const int* in_sizes, int n_in,
                              void* d_out, int out_size, void* d_ws,
                              size_t ws_size, hipStream_t stream) {
  const int* X = (const int*)d_in[0];
  const float* emb = (const float*)d_in[1];
  const float* W_xh = (const float*)d_in[2];
  const float* W_hh = (const float*)d_in[3];
  const float* W_hy = (const float*)d_in[4];
  const float* b_h = (const float*)d_in[5];
  const float* b_y = (const float*)d_in[6];
  float* out = (float*)d_out;

  __hip_bfloat16* hA_hi = (__hip_bfloat16*)d_ws;
  __hip_bfloat16* hA_lo = hA_hi + BATCH * HID;
  __hip_bfloat16* hB_hi = hA_lo + BATCH * HID;
  __hip_bfloat16* hB_lo = hB_hi + BATCH * HID;

  dim3 blk(1024), grd(128);
  layer_kernel<EMB, true><<<grd, blk, 0, stream>>>(
      X, emb, nullptr, nullptr, W_xh, b_h, hA_hi, hA_lo);
  layer_kernel<HID, false><<<grd, blk, 0, stream>>>(
      nullptr, nullptr, hA_hi, hA_lo, W_hh, b_h, hB_hi, hB_lo);
  layer_kernel<HID, false><<<grd, blk, 0, stream>>>(
      nullptr, nullptr, hB_hi, hB_lo, W_hh, b_h, hA_hi, hA_lo);
  layer_kernel<HID, false><<<grd, blk, 0, stream>>>(
      nullptr, nullptr, hA_hi, hA_lo, W_hh, b_h, hB_hi, hB_lo);
  layer_kernel<HID, false><<<grd, blk, 0, stream>>>(
      nullptr, nullptr, hB_hi, hB_lo, W_hh, b_h, hA_hi, hA_lo);
  out_kernel<<<dim3(1000), dim3(256), 0, stream>>>(hA_hi, hA_lo, W_hy, b_y, out);
}

// Round 5
// 197.600 us; speedup vs baseline: 1.4817x; 1.1858x over previous
//
#include <hip/hip_runtime.h>
#include <hip/hip_bf16.h>

#define BATCH 64
#define SEQT  512
#define EMB   1024
#define HID   2048
#define VOC   32000

using bf16x8 = __attribute__((ext_vector_type(8))) __bf16;
using f32x4  = __attribute__((ext_vector_type(4))) float;
using f32x16 = __attribute__((ext_vector_type(16))) float;

__device__ __forceinline__ void split2(float x, __bf16& hi, __bf16& lo) {
  hi = (__bf16)x;
  lo = (__bf16)(x - (float)hi);
}

__device__ __forceinline__ void gload_lds16(const float* g, float* l) {
  __builtin_amdgcn_global_load_lds(
      (const __attribute__((address_space(1))) void*)g,
      (__attribute__((address_space(3))) void*)l, 16, 0, 0);
}

// ---------------------------------------------------------------------------
// Layer kernel (unchanged from round 4): h_out = tanh(A @ W + bias),
// split-bf16, 16x16x32 MFMA, 128 blocks x 16 waves, LDS reduce.
// ---------------------------------------------------------------------------
template <int KTOT, bool GATHER>
__global__ __launch_bounds__(1024) void layer_kernel(
    const int* __restrict__ X, const float* __restrict__ emb,
    const __hip_bfloat16* __restrict__ hin_hi,
    const __hip_bfloat16* __restrict__ hin_lo,
    const float* __restrict__ W, const float* __restrict__ bias,
    __hip_bfloat16* __restrict__ hout_hi,
    __hip_bfloat16* __restrict__ hout_lo) {
  constexpr int KCHUNK = KTOT / 16;
  constexpr int KSTEPS = KCHUNK / 32;
  __shared__ float red[16 * 16 * 72];

  const int tid = threadIdx.x;
  const int w = tid >> 6;
  const int l = tid & 63;
  const int ln = l & 15;
  const int lg = l >> 4;
  const int n0 = blockIdx.x * 16;

  f32x4 acc[4];
#pragma unroll
  for (int mt = 0; mt < 4; ++mt) acc[mt] = f32x4{0.f, 0.f, 0.f, 0.f};

  const float* grow[4];
#pragma unroll
  for (int mt = 0; mt < 4; ++mt) {
    if constexpr (GATHER) {
      const int m = ln + 16 * mt;
      const int tok = X[m * SEQT + (SEQT - 1)];
      grow[mt] = emb + (size_t)tok * EMB;
    } else {
      grow[mt] = nullptr;
    }
  }

  const int kwave = w * KCHUNK + lg * 8;
  const float* Wc = W + n0 + ln;

  float wv[KSTEPS * 8];
#pragma unroll
  for (int j = 0; j < KSTEPS * 8; ++j)
    wv[j] = Wc[(size_t)(kwave + (j >> 3) * 32 + (j & 7)) * HID];

  f32x4 gv[GATHER ? KSTEPS * 8 : 1];
  if constexpr (GATHER) {
#pragma unroll
    for (int ks = 0; ks < KSTEPS; ++ks)
#pragma unroll
      for (int mt = 0; mt < 4; ++mt) {
        const float* p = grow[mt] + kwave + ks * 32;
        gv[(ks * 4 + mt) * 2 + 0] = *reinterpret_cast<const f32x4*>(p);
        gv[(ks * 4 + mt) * 2 + 1] = *reinterpret_cast<const f32x4*>(p + 4);
      }
  }

#pragma unroll
  for (int ks = 0; ks < KSTEPS; ++ks) {
    bf16x8 bhi, blo;
#pragma unroll
    for (int i = 0; i < 8; ++i) {
      __bf16 h_, l_;
      split2(wv[ks * 8 + i], h_, l_);
      bhi[i] = h_;
      blo[i] = l_;
    }
    const int kb = kwave + ks * 32;

#pragma unroll
    for (int mt = 0; mt < 4; ++mt) {
      bf16x8 ahi, alo;
      if constexpr (GATHER) {
        const f32x4 v0 = gv[(ks * 4 + mt) * 2 + 0];
        const f32x4 v1 = gv[(ks * 4 + mt) * 2 + 1];
#pragma unroll
        for (int i = 0; i < 4; ++i) {
          __bf16 h_, l_;
          split2(v0[i], h_, l_);
          ahi[i] = h_; alo[i] = l_;
          split2(v1[i], h_, l_);
          ahi[4 + i] = h_; alo[4 + i] = l_;
        }
      } else {
        const size_t off = (size_t)(ln + 16 * mt) * KTOT + kb;
        ahi = *reinterpret_cast<const bf16x8*>(hin_hi + off);
        alo = *reinterpret_cast<const bf16x8*>(hin_lo + off);
      }
      acc[mt] = __builtin_amdgcn_mfma_f32_16x16x32_bf16(ahi, bhi, acc[mt], 0, 0, 0);
      acc[mt] = __builtin_amdgcn_mfma_f32_16x16x32_bf16(alo, bhi, acc[mt], 0, 0, 0);
      acc[mt] = __builtin_amdgcn_mfma_f32_16x16x32_bf16(ahi, blo, acc[mt], 0, 0, 0);
    }
  }

  float* dst = &red[(w * 16 + ln) * 72 + lg * 4];
#pragma unroll
  for (int mt = 0; mt < 4; ++mt)
    *reinterpret_cast<f32x4*>(dst + mt * 16) = acc[mt];

  __syncthreads();

  {
    const int m = tid >> 4, n = tid & 15;
    float s = 0.f;
#pragma unroll
    for (int ww = 0; ww < 16; ++ww) s += red[(ww * 16 + n) * 72 + m];
    s += bias[n0 + n];
    const float hval = tanhf(s);
    __bf16 h_, l_;
    split2(hval, h_, l_);
    const size_t off = (size_t)m * HID + (n0 + n);
    hout_hi[off] = *reinterpret_cast<__hip_bfloat16*>(&h_);
    hout_lo[off] = *reinterpret_cast<__hip_bfloat16*>(&l_);
  }
}

// ---------------------------------------------------------------------------
// Output kernel v2: out[64][VOC] = h @ W_hy + b_y.
// 250 blocks x 256 thr (4 waves). Block: BN=128 cols, full K=2048 in 64
// stages of BK=32. W-tile [32][128] f32 staged to LDS via global_load_lds
// (16 B), TRIPLE-buffered; raw s_barrier + counted vmcnt(16) keeps 2 stages
// (32 KB) in flight across barriers. Each wave owns one 32-col n-subtile,
// full-K accumulate (no reduce), split-bf16 (3 MFMA), 32x32x16 MFMA.
// A-frags (h, L2-resident) prefetched one stage ahead into named reg sets.
// vmcnt queue/iter: [A(t+1):8][S(t+2):4]; vmcnt(16) leaves S(t+1)+A(t+1)+
// S(t+2), drains S(t)+A(t). 2 wrap stages pad counts uniform.
// ---------------------------------------------------------------------------
struct Afrag {
  bf16x8 h0[2], l0[2], h1[2], l1[2];  // [kstep], rows ln and ln+32
};

__device__ __forceinline__ void load_afrag(
    Afrag& a, const __hip_bfloat16* __restrict__ h_hi,
    const __hip_bfloat16* __restrict__ h_lo, int kg, int ln, int lg) {
#pragma unroll
  for (int ks = 0; ks < 2; ++ks) {
    const size_t o0 = (size_t)ln * HID + kg + ks * 16 + lg * 8;
    const size_t o1 = (size_t)(ln + 32) * HID + kg + ks * 16 + lg * 8;
    a.h0[ks] = *reinterpret_cast<const bf16x8*>(h_hi + o0);
    a.l0[ks] = *reinterpret_cast<const bf16x8*>(h_lo + o0);
    a.h1[ks] = *reinterpret_cast<const bf16x8*>(h_hi + o1);
    a.l1[ks] = *reinterpret_cast<const bf16x8*>(h_lo + o1);
  }
}

__global__ __launch_bounds__(256) void out_kernel(
    const __hip_bfloat16* __restrict__ h_hi,
    const __hip_bfloat16* __restrict__ h_lo, const float* __restrict__ Why,
    const float* __restrict__ by, float* __restrict__ out) {
  __shared__ float lds[3 * 32 * 128];  // 3 x 16 KB W tiles

  const int tid = threadIdx.x;
  const int w = tid >> 6;
  const int l = tid & 63;
  const int ln = l & 31;
  const int lg = l >> 5;
  const int n0 = blockIdx.x * 128;
  const int nw = w * 32;

  f32x16 acc0, acc1;
#pragma unroll
  for (int i = 0; i < 16; ++i) {
    acc0[i] = 0.f;
    acc1[i] = 0.f;
  }

  // per-wave staging: 4 insts, rows w*8 + inst*2 + (l>=32), cols (l&31)*4
  const int srow = w * 8 + lg;          // + inst*2
  const int scol = ln * 4;
  const float* gbase = Why + (size_t)srow * VOC + n0 + scol;

#define STAGE(t_)                                                           \
  {                                                                         \
    const int k0_ = ((t_) & 63) * 32;                                       \
    float* lb_ = lds + ((t_) % 3) * (32 * 128);                             \
    _Pragma("unroll") for (int inst = 0; inst < 4; ++inst) {                \
      gload_lds16(gbase + (size_t)(k0_ + inst * 2) * VOC,                   \
                  lb_ + (w * 8 + inst * 2) * 128);                          \
    }                                                                       \
  }

#define COMPUTE(t_, A_)                                                     \
  {                                                                         \
    const float* lb_ = lds + ((t_) % 3) * (32 * 128);                       \
    _Pragma("unroll") for (int ks = 0; ks < 2; ++ks) {                      \
      float wv_[8];                                                         \
      _Pragma("unroll") for (int i = 0; i < 8; ++i)                         \
          wv_[i] = lb_[(ks * 16 + lg * 8 + i) * 128 + nw + ln];             \
      bf16x8 bhi_, blo_;                                                    \
      _Pragma("unroll") for (int i = 0; i < 8; ++i) {                       \
        __bf16 h_, l_;                                                      \
        split2(wv_[i], h_, l_);                                             \
        bhi_[i] = h_;                                                       \
        blo_[i] = l_;                                                       \
      }                                                                     \
      acc0 = __builtin_amdgcn_mfma_f32_32x32x16_bf16(A_.h0[ks], bhi_, acc0, 0, 0, 0); \
      acc0 = __builtin_amdgcn_mfma_f32_32x32x16_bf16(A_.l0[ks], bhi_, acc0, 0, 0, 0); \
      acc0 = __builtin_amdgcn_mfma_f32_32x32x16_bf16(A_.h0[ks], blo_, acc0, 0, 0, 0); \
      acc1 = __builtin_amdgcn_mfma_f32_32x32x16_bf16(A_.h1[ks], bhi_, acc1, 0, 0, 0); \
      acc1 = __builtin_amdgcn_mfma_f32_32x32x16_bf16(A_.l1[ks], bhi_, acc1, 0, 0, 0); \
      acc1 = __builtin_amdgcn_mfma_f32_32x32x16_bf16(A_.h1[ks], blo_, acc1, 0, 0, 0); \
    }                                                                       \
  }

#define ITER(t_, Acur_, Anxt_)                                              \
  {                                                                         \
    load_afrag(Anxt_, h_hi, h_lo, (((t_) + 1) & 63) * 32, ln, lg);          \
    STAGE((t_) + 2);                                                        \
    asm volatile("s_waitcnt vmcnt(16)" ::: "memory");                       \
    __builtin_amdgcn_s_barrier();                                           \
    __builtin_amdgcn_sched_barrier(0);                                      \
    COMPUTE(t_, Acur_);                                                     \
    __builtin_amdgcn_s_barrier();                                           \
  }

  Afrag Aa, Ab;
  // prologue: stages 0,1 + A(0)   queue: [S0:4][S1:4][A0:8]
  STAGE(0);
  STAGE(1);
  load_afrag(Aa, h_hi, h_lo, 0, ln, lg);

  for (int t = 0; t < 64; t += 2) {
    ITER(t, Aa, Ab);
    ITER(t + 1, Ab, Aa);
  }

  // epilogue: direct store (full-K acc per wave), rows j+8q+4lg, col nw+ln
  const int col = n0 + nw + ln;
  const float bval = by[col];
#pragma unroll
  for (int q = 0; q < 4; ++q) {
#pragma unroll
    for (int j = 0; j < 4; ++j) {
      const int row = j + 8 * q + 4 * lg;
      __builtin_nontemporal_store(acc0[4 * q + j] + bval,
                                  out + (size_t)row * VOC + col);
      __builtin_nontemporal_store(acc1[4 * q + j] + bval,
                                  out + (size_t)(row + 32) * VOC + col);
    }
  }
#undef ITER
#undef COMPUTE
#undef STAGE
}

extern "C" void kernel_launch(void* const* d_in, const int* in_sizes, int n_in,
                              void* d_out, int out_size, void* d_ws,
                              size_t ws_size, hipStream_t stream) {
  const int* X = (const int*)d_in[0];
  const float* emb = (const float*)d_in[1];
  const float* W_xh = (const float*)d_in[2];
  const float* W_hh = (const float*)d_in[3];
  const float* W_hy = (const float*)d_in[4];
  const float* b_h = (const float*)d_in[5];
  const float* b_y = (const float*)d_in[6];
  float* out = (float*)d_out;

  __hip_bfloat16* hA_hi = (__hip_bfloat16*)d_ws;
  __hip_bfloat16* hA_lo = hA_hi + BATCH * HID;
  __hip_bfloat16* hB_hi = hA_lo + BATCH * HID;
  __hip_bfloat16* hB_lo = hB_hi + BATCH * HID;

  dim3 blk(1024), grd(128);
  layer_kernel<EMB, true><<<grd, blk, 0, stream>>>(
      X, emb, nullptr, nullptr, W_xh, b_h, hA_hi, hA_lo);
  layer_kernel<HID, false><<<grd, blk, 0, stream>>>(
      nullptr, nullptr, hA_hi, hA_lo, W_hh, b_h, hB_hi, hB_lo);
  layer_kernel<HID, false><<<grd, blk, 0, stream>>>(
      nullptr, nullptr, hB_hi, hB_lo, W_hh, b_h, hA_hi, hA_lo);
  layer_kernel<HID, false><<<grd, blk, 0, stream>>>(
      nullptr, nullptr, hA_hi, hA_lo, W_hh, b_h, hB_hi, hB_lo);
  layer_kernel<HID, false><<<grd, blk, 0, stream>>>(
      nullptr, nullptr, hB_hi, hB_lo, W_hh, b_h, hA_hi, hA_lo);
  out_kernel<<<dim3(250), dim3(256), 0, stream>>>(hA_hi, hA_lo, W_hy, b_y, out);
}

// Round 7
// 169.369 us; speedup vs baseline: 1.7287x; 1.1667x over previous
//
#include <hip/hip_runtime.h>
#include <hip/hip_bf16.h>

#define BATCH 64
#define SEQT  512
#define EMB   1024
#define HID   2048
#define VOC   32000
#define KSPLIT 8

using bf16x8 = __attribute__((ext_vector_type(8))) __bf16;
using f32x4  = __attribute__((ext_vector_type(4))) float;

__device__ __forceinline__ void split2(float x, __bf16& hi, __bf16& lo) {
  hi = (__bf16)x;
  lo = (__bf16)(x - (float)hi);
}

__device__ __forceinline__ float bfu2f(unsigned u16) {
  const unsigned u = u16 << 16;
  return __builtin_bit_cast(float, u);
}

// ---------------------------------------------------------------------------
// Layer kernel: h_out = tanh(A @ W + bias), split-bf16 (3 MFMA products,
// f32 accumulate), 16x16x32 MFMA. 256 blocks = 128 N-tiles x 2 M-halves,
// 1024 thr = 16 waves, K-split 16 within block, LDS reduce. All W AND A
// loads hoisted ahead of compute -> single latency exposure per wave.
// ---------------------------------------------------------------------------
template <int KTOT, bool GATHER>
__global__ __launch_bounds__(1024) void layer_kernel(
    const int* __restrict__ X, const float* __restrict__ emb,
    const __hip_bfloat16* __restrict__ hin_hi,
    const __hip_bfloat16* __restrict__ hin_lo,
    const float* __restrict__ W, const float* __restrict__ bias,
    __hip_bfloat16* __restrict__ hout_hi,
    __hip_bfloat16* __restrict__ hout_lo) {
  constexpr int KCHUNK = KTOT / 16;   // 128 (HID) / 64 (EMB)
  constexpr int KSTEPS = KCHUNK / 32; // 4 / 2
  __shared__ float red[16 * 16 * 40];  // [wave][n][m_local pad 32->40]

  const int tid = threadIdx.x;
  const int w = tid >> 6;
  const int l = tid & 63;
  const int ln = l & 15;
  const int lg = l >> 4;
  const int n0 = (blockIdx.x & 127) * 16;
  const int mb = (blockIdx.x >> 7) * 32;  // M-half base

  f32x4 acc[2];
#pragma unroll
  for (int mt = 0; mt < 2; ++mt) acc[mt] = f32x4{0.f, 0.f, 0.f, 0.f};

  const float* grow[2];
#pragma unroll
  for (int mt = 0; mt < 2; ++mt) {
    if constexpr (GATHER) {
      const int m = mb + ln + 16 * mt;
      const int tok = X[m * SEQT + (SEQT - 1)];
      grow[mt] = emb + (size_t)tok * EMB;
    } else {
      grow[mt] = nullptr;
    }
  }

  const int kwave = w * KCHUNK + lg * 8;
  const float* Wc = W + n0 + ln;

  // hoist ALL W loads for this wave's K-chunk
  float wv[KSTEPS * 8];
#pragma unroll
  for (int j = 0; j < KSTEPS * 8; ++j)
    wv[j] = Wc[(size_t)(kwave + (j >> 3) * 32 + (j & 7)) * HID];

  // hoist ALL A fragments (split-bf16 planes)
  bf16x8 Ah[2][KSTEPS], Al[2][KSTEPS];
  if constexpr (GATHER) {
#pragma unroll
    for (int mt = 0; mt < 2; ++mt)
#pragma unroll
      for (int ks = 0; ks < KSTEPS; ++ks) {
        const float* p = grow[mt] + kwave + ks * 32;
        const f32x4 v0 = *reinterpret_cast<const f32x4*>(p);
        const f32x4 v1 = *reinterpret_cast<const f32x4*>(p + 4);
#pragma unroll
        for (int i = 0; i < 4; ++i) {
          __bf16 h_, l_;
          split2(v0[i], h_, l_);
          Ah[mt][ks][i] = h_;
          Al[mt][ks][i] = l_;
          split2(v1[i], h_, l_);
          Ah[mt][ks][4 + i] = h_;
          Al[mt][ks][4 + i] = l_;
        }
      }
  } else {
#pragma unroll
    for (int mt = 0; mt < 2; ++mt)
#pragma unroll
      for (int ks = 0; ks < KSTEPS; ++ks) {
        const size_t off = (size_t)(mb + ln + 16 * mt) * KTOT + kwave + ks * 32;
        Ah[mt][ks] = *reinterpret_cast<const bf16x8*>(hin_hi + off);
        Al[mt][ks] = *reinterpret_cast<const bf16x8*>(hin_lo + off);
      }
  }

#pragma unroll
  for (int ks = 0; ks < KSTEPS; ++ks) {
    bf16x8 bhi, blo;
#pragma unroll
    for (int i = 0; i < 8; ++i) {
      __bf16 h_, l_;
      split2(wv[ks * 8 + i], h_, l_);
      bhi[i] = h_;
      blo[i] = l_;
    }
#pragma unroll
    for (int mt = 0; mt < 2; ++mt) {
      acc[mt] = __builtin_amdgcn_mfma_f32_16x16x32_bf16(Ah[mt][ks], bhi, acc[mt], 0, 0, 0);
      acc[mt] = __builtin_amdgcn_mfma_f32_16x16x32_bf16(Al[mt][ks], bhi, acc[mt], 0, 0, 0);
      acc[mt] = __builtin_amdgcn_mfma_f32_16x16x32_bf16(Ah[mt][ks], blo, acc[mt], 0, 0, 0);
    }
  }

  // stash: red[(w*16+n)*40 + m_local]; acc[mt][j] -> m_local = mt*16+lg*4+j
  float* dst = &red[(w * 16 + ln) * 40 + lg * 4];
#pragma unroll
  for (int mt = 0; mt < 2; ++mt)
    *reinterpret_cast<f32x4*>(dst + mt * 16) = acc[mt];

  __syncthreads();

  if (tid < 512) {
    const int m = tid >> 4, n = tid & 15;  // m_local 0..31
    float s = 0.f;
#pragma unroll
    for (int ww = 0; ww < 16; ++ww) s += red[(ww * 16 + n) * 40 + m];
    s += bias[n0 + n];
    const float hval = tanhf(s);
    __bf16 h_, l_;
    split2(hval, h_, l_);
    const size_t off = (size_t)(mb + m) * HID + (n0 + n);
    hout_hi[off] = *reinterpret_cast<__hip_bfloat16*>(&h_);
    hout_lo[off] = *reinterpret_cast<__hip_bfloat16*>(&l_);
  }
}

// ---------------------------------------------------------------------------
// pack_h: combine split-bf16 h -> f16x2 pairs hp[kp][64 m] (for dot2) and
// f32 hf[k][64 m] (fmaf fallback). 256 blocks x 256 thr.
// ---------------------------------------------------------------------------
__global__ __launch_bounds__(256) void pack_h(
    const __hip_bfloat16* __restrict__ h_hi,
    const __hip_bfloat16* __restrict__ h_lo, unsigned* __restrict__ hp,
    float* __restrict__ hf) {
  const int t = blockIdx.x * 256 + threadIdx.x;  // 65536 = 64 m x 1024 kp
  const int kp = t & 1023, m = t >> 10;
  const unsigned uh =
      *reinterpret_cast<const unsigned*>(h_hi + (size_t)m * HID + 2 * kp);
  const unsigned ul =
      *reinterpret_cast<const unsigned*>(h_lo + (size_t)m * HID + 2 * kp);
  const float v0 = bfu2f(uh & 0xffffu) + bfu2f(ul & 0xffffu);
  const float v1 = bfu2f(uh >> 16) + bfu2f(ul >> 16);
  hp[kp * 64 + m] =
      __builtin_bit_cast(unsigned, __builtin_amdgcn_cvt_pkrtz(v0, v1));
  hf[(size_t)(2 * kp) * 64 + m] = v0;
  hf[(size_t)(2 * kp + 1) * 64 + m] = v1;
}

// ---------------------------------------------------------------------------
// out_main: scratch[kq][m][n] = h[:,kq-range] @ W_hy[kq-range,:].
// Pure VALU streaming: lane owns col n, reads W coalesced/nontemporal,
// h comes through the SCALAR pipe (uniform address -> s_load_dwordx16),
// v_dot2_f32_f16 (4 FLOP/inst) or fmaf fallback. No LDS, no barriers.
// Grid: 125 n-tiles x KSPLIT(8) = 1000 blocks x 256 thr.
// ---------------------------------------------------------------------------
__global__ __launch_bounds__(256) void out_main(
    const unsigned* __restrict__ hp, const float* __restrict__ hf,
    const float* __restrict__ Why, float* __restrict__ scratch) {
  const int tid = threadIdx.x;
  const int nt = blockIdx.x % 125;
  const int kq = blockIdx.x / 125;
  const int n = nt * 256 + tid;

  float acc[64];
#pragma unroll
  for (int m = 0; m < 64; ++m) acc[m] = 0.f;

#if __has_builtin(__builtin_amdgcn_fdot2)
  using h2  = __attribute__((ext_vector_type(2))) _Float16;
  using fp2 = __attribute__((ext_vector_type(2))) __fp16;
  const int kp0 = kq * (HID / KSPLIT / 2);  // 128 k-pairs per block
  const float* W0 = Why + n;
#pragma unroll 2
  for (int kp = kp0; kp < kp0 + HID / KSPLIT / 2; ++kp) {
    const float w0 = __builtin_nontemporal_load(W0 + (size_t)(2 * kp) * VOC);
    const float w1 = __builtin_nontemporal_load(W0 + (size_t)(2 * kp + 1) * VOC);
    const fp2 wp_raw = __builtin_amdgcn_cvt_pkrtz(w0, w1);
    const h2 wp = __builtin_bit_cast(h2, wp_raw);
    const unsigned* hk = hp + kp * 64;
#pragma unroll
    for (int m = 0; m < 64; ++m) {
      acc[m] = __builtin_amdgcn_fdot2(wp, __builtin_bit_cast(h2, hk[m]),
                                      acc[m], false);
    }
  }
#else
  const int k0 = kq * (HID / KSPLIT);
  const float* W0 = Why + n;
#pragma unroll 2
  for (int k = k0; k < k0 + HID / KSPLIT; ++k) {
    const float wv = __builtin_nontemporal_load(W0 + (size_t)k * VOC);
    const float* hk = hf + (size_t)k * 64;
#pragma unroll
    for (int m = 0; m < 64; ++m) acc[m] = fmaf(wv, hk[m], acc[m]);
  }
#endif

  float* sc = scratch + (size_t)kq * ((size_t)BATCH * VOC) + n;
#pragma unroll
  for (int m = 0; m < 64; ++m) sc[(size_t)m * VOC] = acc[m];
}

// ---------------------------------------------------------------------------
// reduce_out: out[m][n] = sum_q scratch[q][m][n] + b_y[n].
// Grid (125, 64) x 256 thr; scratch is L3-hot.
// ---------------------------------------------------------------------------
__global__ __launch_bounds__(256) void reduce_out(
    const float* __restrict__ scratch, const float* __restrict__ by,
    float* __restrict__ out) {
  const int n = blockIdx.x * 256 + threadIdx.x;
  const int m = blockIdx.y;
  float s = by[n];
#pragma unroll
  for (int q = 0; q < KSPLIT; ++q)
    s += scratch[(size_t)q * ((size_t)BATCH * VOC) + (size_t)m * VOC + n];
  __builtin_nontemporal_store(s, out + (size_t)m * VOC + n);
}

extern "C" void kernel_launch(void* const* d_in, const int* in_sizes, int n_in,
                              void* d_out, int out_size, void* d_ws,
                              size_t ws_size, hipStream_t stream) {
  const int* X = (const int*)d_in[0];
  const float* emb = (const float*)d_in[1];
  const float* W_xh = (const float*)d_in[2];
  const float* W_hh = (const float*)d_in[3];
  const float* W_hy = (const float*)d_in[4];
  const float* b_h = (const float*)d_in[5];
  const float* b_y = (const float*)d_in[6];
  float* out = (float*)d_out;

  char* ws = (char*)d_ws;
  const size_t PLANE = (size_t)BATCH * HID;  // elements
  __hip_bfloat16* hA_hi = (__hip_bfloat16*)ws;
  __hip_bfloat16* hA_lo = hA_hi + PLANE;
  __hip_bfloat16* hB_hi = hA_lo + PLANE;
  __hip_bfloat16* hB_lo = hB_hi + PLANE;
  char* p = ws + 4 * PLANE * sizeof(__hip_bfloat16);
  unsigned* hp = (unsigned*)p;                 // 64*1024 u32
  p += (size_t)BATCH * (HID / 2) * sizeof(unsigned);
  float* hf = (float*)p;                       // 2048*64 f32
  p += (size_t)HID * BATCH * sizeof(float);
  float* scratch = (float*)p;                  // KSPLIT*64*32000 f32

  dim3 blk(1024), grd(256);
  layer_kernel<EMB, true><<<grd, blk, 0, stream>>>(
      X, emb, nullptr, nullptr, W_xh, b_h, hA_hi, hA_lo);
  layer_kernel<HID, false><<<grd, blk, 0, stream>>>(
      nullptr, nullptr, hA_hi, hA_lo, W_hh, b_h, hB_hi, hB_lo);
  layer_kernel<HID, false><<<grd, blk, 0, stream>>>(
      nullptr, nullptr, hB_hi, hB_lo, W_hh, b_h, hA_hi, hA_lo);
  layer_kernel<HID, false><<<grd, blk, 0, stream>>>(
      nullptr, nullptr, hA_hi, hA_lo, W_hh, b_h, hB_hi, hB_lo);
  layer_kernel<HID, false><<<grd, blk, 0, stream>>>(
      nullptr, nullptr, hB_hi, hB_lo, W_hh, b_h, hA_hi, hA_lo);

  pack_h<<<dim3(256), dim3(256), 0, stream>>>(hA_hi, hA_lo, hp, hf);
  out_main<<<dim3(125 * KSPLIT), dim3(256), 0, stream>>>(hp, hf, W_hy, scratch);
  reduce_out<<<dim3(125, 64), dim3(256), 0, stream>>>(scratch, b_y, out);
}